// Round 14
// baseline (437.516 us; speedup 1.0000x reference)
//
#include <hip/hip_runtime.h>
#include <hip/hip_bf16.h>
#include <math.h>

// Problem constants
#define RM 64512            // B*N*PN = 1024*63 rows through the transformer
// B=8 N=128 L=512 PN=63 PL=16 ST=8 DM=128 H=16 DK=8 DFF=256 NL=2 DG=8 MP=3 TW=96

typedef short short8 __attribute__((ext_vector_type(8)));
typedef float f32x4 __attribute__((ext_vector_type(4)));
typedef unsigned short ushort4v __attribute__((ext_vector_type(4)));
typedef unsigned short ushort8v __attribute__((ext_vector_type(8)));

__device__ __forceinline__ float gelu_f(float v) {
    return 0.5f * v * (1.0f + erff(v * 0.70710678118654752f));
}
__device__ __forceinline__ float b2f(unsigned short u) {
    unsigned int x = ((unsigned int)u) << 16;
    return __builtin_bit_cast(float, x);
}
__device__ __forceinline__ unsigned short f2b(float f) {
    __hip_bfloat16 h = __float2bfloat16(f);   // RNE
    return __builtin_bit_cast(unsigned short, h);
}

// ---------------- Fused DGCN v3 + weight prep (blocks >= 4096) ----------------
__global__ __launch_bounds__(256) void dgcn_kernel(
    const float* __restrict__ x, const float* __restrict__ adj,
    const float* __restrict__ sw, const float* __restrict__ sb,
    const float* __restrict__ mw, const float* __restrict__ mb,
    float* __restrict__ y,
    const float* __restrict__ Wq, const float* __restrict__ Wk, const float* __restrict__ Wv,
    const float* __restrict__ Wo, const float* __restrict__ fw1, const float* __restrict__ fw2,
    const float* __restrict__ bq, const float* __restrict__ bk, const float* __restrict__ bv,
    unsigned short* __restrict__ WB, float* __restrict__ bcat)
{
    if (blockIdx.x >= 4096) {
        const int wb = blockIdx.x - 4096;
        const int id = wb / 64, bx = wb % 64;
        const int l = id / 6, mat = id % 6;
        const float* src; int K, N; size_t off = (size_t)l * 131072;
        switch (mat) {
            case 0: src = Wq  + l*16384; K = 128; N = 128; off += 0;      break;
            case 1: src = Wk  + l*16384; K = 128; N = 128; off += 16384;  break;
            case 2: src = Wv  + l*16384; K = 128; N = 128; off += 32768;  break;
            case 3: src = Wo  + l*16384; K = 128; N = 128; off += 49152;  break;
            case 4: src = fw1 + l*32768; K = 128; N = 256; off += 65536;  break;
            default:src = fw2 + l*32768; K = 256; N = 128; off += 98304;  break;
        }
        const int total = K * N;
        const int ksh = (K == 256) ? 8 : 7;
        for (int idx = bx*256 + threadIdx.x; idx < total; idx += 64*256) {
            int n = idx >> ksh, k = idx & (K - 1);
            WB[off + idx] = f2b(src[(size_t)k*N + n]);
        }
        if (id == 0 && bx == 0) {
            for (int idx = threadIdx.x; idx < 768; idx += 256) {
                int ll = idx / 384, j = idx % 384;
                float vv;
                if (j < 128)      vv = bq[ll*128 + j];
                else if (j < 256) vv = bk[ll*128 + j - 128];
                else              vv = bv[ll*128 + j - 256];
                bcat[idx] = vv;
            }
        }
        return;
    }
    __shared__ __align__(16) unsigned short ET[128*128];  // 32 KB
    __shared__ __align__(16) unsigned short hT[16*128];   // 4 KB
    __shared__ float red[256];
    __shared__ float iv[128];
    __shared__ float xc[128];
    __shared__ float yac[128];
    const int bid = blockIdx.x;            // b*512 + s
    const int b = bid >> 9, s = bid & 511;
    const int t = threadIdx.x;
    const int lane = t & 63, wid = t >> 6;
    const float* ap = adj + (size_t)bid * 16384;

    if (t < 128) xc[t] = x[((size_t)b*128 + t)*512 + s];

    // Phase 1: exp + transpose-write (swizzled) + colsum partials
    {
        const int m = t & 127, ng = t >> 7;
        float sm = 0.f;
        for (int p = 0; p < 16; ++p) {
            const int n0 = p*8 + ng*4;
            float e0 = __expf(ap[(size_t)(n0+0)*128 + m]);
            float e1 = __expf(ap[(size_t)(n0+1)*128 + m]);
            float e2 = __expf(ap[(size_t)(n0+2)*128 + m]);
            float e3 = __expf(ap[(size_t)(n0+3)*128 + m]);
            sm += e0 + e1 + e2 + e3;
            ushort4v u4; u4[0]=f2b(e0); u4[1]=f2b(e1); u4[2]=f2b(e2); u4[3]=f2b(e3);
            *(ushort4v*)((char*)ET + m*256 + (((n0>>3) ^ (m & 15))*16) + (n0 & 7)*2) = u4;
        }
        red[ng*128 + m] = sm;
        *(ushort4v*)&hT[8*128 + t*4] = (ushort4v){0,0,0,0};
    }
    __syncthreads();
    if (t < 128) iv[t] = 1.f / (red[t] + red[128 + t]);
    // Phase 2: h0 + y0 + hT rows 0..7
    if (t < 128) {
        const int m = t;
        const float xm = xc[m];
        float yp = 0.f;
        #pragma unroll
        for (int c = 0; c < 8; ++c) {
            float h = xm*sw[c] + sb[c];
            yp += h*mw[c];
            *(unsigned short*)((char*)hT + c*256 + ((((m>>3) ^ c))*16) + (m & 7)*2) = f2b(h);
        }
        yac[m] = yp;
    }
    __syncthreads();

    // Phase 3: 3 MFMA propagation steps. Wave wid owns m-tiles {2wid, 2wid+1}.
    const int rl = lane & 15, kh = lane >> 4;
    short8 af[2][4];
    float xr[2][4], ivr[2][4];
    #pragma unroll
    for (int ti = 0; ti < 2; ++ti) {
        const int mrow = (wid*2 + ti)*16 + rl;
        #pragma unroll
        for (int ks = 0; ks < 4; ++ks) {
            const int ch = (ks*4 + kh) ^ (mrow & 15);
            af[ti][ks] = *(const short8*)((const char*)ET + mrow*256 + ch*16);
        }
        #pragma unroll
        for (int r = 0; r < 4; ++r) {
            const int m = (wid*2 + ti)*16 + kh*4 + r;
            xr[ti][r]  = 0.05f * xc[m];
            ivr[ti][r] = 0.95f * iv[m];
        }
    }
    float yl[2][4] = {};
    #pragma unroll
    for (int step = 1; step <= 3; ++step) {
        short8 bfr[4];
        #pragma unroll
        for (int ks = 0; ks < 4; ++ks) {
            const int ch = (ks*4 + kh) ^ rl;
            bfr[ks] = *(const short8*)((const char*)hT + rl*256 + ch*16);
        }
        f32x4 acc[2] = {};
        #pragma unroll
        for (int ti = 0; ti < 2; ++ti)
            #pragma unroll
            for (int ks = 0; ks < 4; ++ks)
                acc[ti] = __builtin_amdgcn_mfma_f32_16x16x32_bf16(af[ti][ks], bfr[ks], acc[ti], 0, 0, 0);
        __syncthreads();
        const float mwc = (rl < 8) ? mw[step*8 + rl] : 0.f;
        #pragma unroll
        for (int ti = 0; ti < 2; ++ti) {
            const int m0 = (wid*2 + ti)*16 + kh*4;
            ushort4v hw4;
            float hnew[4];
            #pragma unroll
            for (int r = 0; r < 4; ++r) {
                float v = xr[ti][r] + ivr[ti][r]*acc[ti][r];
                hnew[r] = v;
                hw4[r] = f2b(v);
            }
            *(ushort4v*)((char*)hT + rl*256 + (((m0>>3) ^ rl)*16) + (m0 & 7)*2) = hw4;
            #pragma unroll
            for (int r = 0; r < 4; ++r) {
                float vv = hnew[r]*mwc;
                vv += __shfl_xor(vv, 1);
                vv += __shfl_xor(vv, 2);
                vv += __shfl_xor(vv, 4);
                vv += __shfl_xor(vv, 8);
                yl[ti][r] += vv;
            }
        }
        __syncthreads();
    }
    if (rl == 0) {
        #pragma unroll
        for (int ti = 0; ti < 2; ++ti)
            #pragma unroll
            for (int r = 0; r < 4; ++r)
                yac[(wid*2 + ti)*16 + kh*4 + r] += yl[ti][r];
    }
    __syncthreads();
    if (t < 128) y[((size_t)b*128 + t)*512 + s] = yac[t] + mb[0];
}

// ---------------- Patch embedding: srcb = bf16(z @ W_P + b_P + W_pos) ----------------
__global__ __launch_bounds__(256) void patch_kernel(
    const float* __restrict__ y, const float* __restrict__ Wp, const float* __restrict__ bp,
    const float* __restrict__ Wpos, unsigned short* __restrict__ srcb)
{
    __shared__ float ys[512];
    __shared__ float wps[16*128];
    const int bn = blockIdx.x;
    const int t = threadIdx.x;
    ys[t]       = y[(size_t)bn*512 + t];
    ys[t + 256] = y[(size_t)bn*512 + t + 256];
    #pragma unroll
    for (int r = 0; r < 8; ++r) wps[t + r*256] = Wp[t + r*256];
    __syncthreads();
    for (int cu = t; cu < 1008; cu += 256) {
        int p = cu >> 4, d0 = (cu & 15) * 8;
        float o[8];
        #pragma unroll
        for (int j = 0; j < 8; ++j) o[j] = bp[d0+j] + Wpos[p*128 + d0 + j];
        #pragma unroll
        for (int tt = 0; tt < 16; ++tt) {
            float a = ys[p*8 + tt];
            #pragma unroll
            for (int j = 0; j < 8; ++j) o[j] += a * wps[tt*128 + d0 + j];
        }
        size_t row = (size_t)bn*63 + p;
        ushort8v u;
        #pragma unroll
        for (int j = 0; j < 8; ++j) u[j] = f2b(o[j]);
        *(ushort8v*)&srcb[row*128 + d0] = u;
    }
}

// ---------------- bf16 MFMA GEMM, BM=64 rows (52 KB LDS -> 3 blocks/CU) ----------------
template<int ACT, int OM, int RESMODE, bool STATS, bool AHM, int NB, int KK>
__global__ __launch_bounds__(256) void mgemm(
    const unsigned short* __restrict__ A, const unsigned short* __restrict__ WB,
    const float* __restrict__ bias, const unsigned short* __restrict__ Rsd,
    const float* __restrict__ snR,
    unsigned short* __restrict__ Cb,
    float* __restrict__ part)
{
    constexpr int NTOT = NB * 128;
    constexpr int kch = KK >> 3;
    constexpr int KT = KK >> 7;
    __shared__ __align__(16) unsigned short AsL[64*128];   // 16 KB
    __shared__ __align__(16) unsigned short BsL[128*128];  // 32 KB
    __shared__ float sred[4][16][8], qred[4][16][8];
    const int t = threadIdx.x;
    const int lane = t & 63, wid = t >> 6;
    const int wr = wid >> 1, wc = wid & 1;
    const int m0 = blockIdx.x * 64;
    const int kh = lane >> 4, rl = lane & 15;
    const int rq = lane >> 4;
    float sj[8] = {}, qj[8] = {};

    for (int ib = 0; ib < NB; ++ib) {
        f32x4 acc[2][4] = {};
        for (int kt = 0; kt < KT; ++kt) {
            if (ib == 0 || KT > 1) {
                #pragma unroll
                for (int i = 0; i < 4; ++i) {
                    int cid = i*256 + t;
                    const unsigned short* ga;
                    if constexpr (AHM) {
                        int hd2 = cid >> 6, row = cid & 63;
                        ga = A + ((size_t)hd2*RM + (m0+row))*8;
                    } else {
                        int row = cid >> 4, c = cid & 15;
                        int c_g = c ^ (row & 7);
                        ga = A + ((size_t)(m0+row)*kch + kt*16 + c_g)*8;
                    }
                    __builtin_amdgcn_global_load_lds((const unsigned int*)ga,
                        (unsigned int*)&AsL[(i*256 + wid*64)*8], 16, 0, 0);
                }
            }
            #pragma unroll
            for (int i = 0; i < 8; ++i) {
                int cid = i*256 + t;
                int nr = cid >> 4, c = cid & 15;
                const unsigned short* gb = WB + (size_t)ib*128*KK
                    + ((size_t)nr*kch + kt*16 + (c ^ (nr & 7)))*8;
                __builtin_amdgcn_global_load_lds((const unsigned int*)gb,
                    (unsigned int*)&BsL[(i*256 + wid*64)*8], 16, 0, 0);
            }
            __syncthreads();
            #pragma unroll
            for (int ks = 0; ks < 4; ++ks) {
                const int cA = ks*4 + kh;
                short8 af[2], bfr[4];
                #pragma unroll
                for (int i = 0; i < 2; ++i) {
                    int row = wr*32 + i*16 + rl;
                    if constexpr (AHM) af[i] = *(const short8*)&AsL[(cA*64 + row)*8];
                    else               af[i] = *(const short8*)&AsL[row*128 + ((cA ^ (row & 7))*8)];
                }
                #pragma unroll
                for (int j = 0; j < 4; ++j) {
                    int cn = wc*64 + j*16 + rl;
                    bfr[j] = *(const short8*)&BsL[cn*128 + ((cA ^ (cn & 7))*8)];
                }
                #pragma unroll
                for (int i = 0; i < 2; ++i)
                    #pragma unroll
                    for (int j = 0; j < 4; ++j)
                        acc[i][j] = __builtin_amdgcn_mfma_f32_16x16x32_bf16(af[i], bfr[j], acc[i][j], 0, 0, 0);
            }
            __syncthreads();
        }
        // E1: repack 64x128 tile into BsL (chunk^row15 swizzle)
        #pragma unroll
        for (int j = 0; j < 4; ++j) {
            const int col_l = wc*64 + j*16 + rl;
            const float bs = bias[ib*128 + col_l];
            const int chunk = col_l >> 3, bo2 = (col_l & 7) << 1;
            #pragma unroll
            for (int i = 0; i < 2; ++i) {
                #pragma unroll
                for (int r = 0; r < 4; ++r) {
                    const int row_l = wr*32 + i*16 + rq*4 + r;
                    float v = acc[i][j][r] + bs;
                    if constexpr (ACT == 1) v = gelu_f(v);
                    *(unsigned short*)((char*)BsL + row_l*256 + ((chunk ^ (row_l & 15))<<4) + bo2) = f2b(v);
                }
            }
        }
        __syncthreads();
        // E2: coalesced read-out
        if constexpr (OM == 1) {
            #pragma unroll
            for (int it = 0; it < 4; ++it) {
                int cid = it*256 + t;
                int row_l = cid & 63, hd_l = cid >> 6;
                ushort8v u = *(const ushort8v*)((const char*)BsL + row_l*256 + ((hd_l ^ (row_l & 15))<<4));
                *(ushort8v*)&Cb[(((size_t)(ib*16 + hd_l))*RM + m0 + row_l)*8] = u;
            }
        } else {
            #pragma unroll
            for (int it = 0; it < 4; ++it) {
                const int row_l = it*16 + (t >> 4), c = t & 15;
                ushort8v u = *(const ushort8v*)((const char*)BsL + row_l*256 + ((c ^ (row_l & 15))<<4));
                const size_t gbase = (size_t)(m0 + row_l)*NTOT + ib*128 + c*8;
                ushort8v rs = {};
                if constexpr (RESMODE != 0) rs = *(const ushort8v*)&Rsd[gbase];
                ushort8v o8;
                #pragma unroll
                for (int jj = 0; jj < 8; ++jj) {
                    float v = b2f(u[jj]);
                    if constexpr (RESMODE == 1) v += b2f(rs[jj]);
                    if constexpr (RESMODE == 2) v += b2f(rs[jj])*snR[c*8+jj] + snR[128 + c*8 + jj];
                    if constexpr (STATS) { sj[jj] += v; qj[jj] += v*v; }
                    o8[jj] = f2b(v);
                }
                *(ushort8v*)&Cb[gbase] = o8;
            }
        }
        __syncthreads();
    }
    if constexpr (STATS) {
        #pragma unroll
        for (int jj = 0; jj < 8; ++jj) {
            sj[jj] += __shfl_xor(sj[jj], 16); qj[jj] += __shfl_xor(qj[jj], 16);
            sj[jj] += __shfl_xor(sj[jj], 32); qj[jj] += __shfl_xor(qj[jj], 32);
        }
        if ((lane >> 4) == 0) {
            #pragma unroll
            for (int jj = 0; jj < 8; ++jj) {
                sred[wid][lane][jj] = sj[jj];
                qred[wid][lane][jj] = qj[jj];
            }
        }
        __syncthreads();
        if (t < 128) {
            const int c2 = t >> 3, jj = t & 7;
            float s = sred[0][c2][jj] + sred[1][c2][jj] + sred[2][c2][jj] + sred[3][c2][jj];
            float q = qred[0][c2][jj] + qred[1][c2][jj] + qred[2][c2][jj] + qred[3][c2][jj];
            part[(size_t)blockIdx.x*256 + t]       = s;
            part[(size_t)blockIdx.x*256 + 128 + t] = q;
        }
    }
}

// ---------------- Fused QKV-GEMM + attention: one block per bn (80 KB LDS -> 2/CU) ----------------
// A [RM][128] bf16; WBq [384][128] bf16 (q,k,v); bias 384.
// L==0: exports q,k slabs to q0k0 [32][RM][8]; L==1: reads q0/k0 for prev scores.
template<int L>
__global__ __launch_bounds__(256) void qkattn(
    const unsigned short* __restrict__ A, const unsigned short* __restrict__ WBq,
    const float* __restrict__ bias, const float* __restrict__ scale,
    const unsigned short* __restrict__ q0k0, unsigned short* __restrict__ q0k0out,
    unsigned short* __restrict__ ob)
{
    __shared__ __align__(16) char smem[81920];             // 80 KB exactly
    unsigned short* AsL = (unsigned short*)smem;            // 16 KB: A 64x128
    unsigned short* BsL = (unsigned short*)(smem + 16384);  // 16 KB: W chunk 64x128 / k0 slabs
    unsigned short* QKV = (unsigned short*)(smem + 32768);  // 48 KB: [48][64][8]
    const int t = threadIdx.x;
    const int lane = t & 63, wid = t >> 6;
    const int bn = blockIdx.x;
    const size_t r0 = (size_t)bn * 63;
    const int kh = lane >> 4, rl = lane & 15, rq = lane >> 4;

    // stage A rows r0..r0+63 (row 63 clamped; garbage contained)
    #pragma unroll
    for (int i = 0; i < 4; ++i) {
        int cid = i*256 + t;
        int row = cid >> 4, c = cid & 15;
        size_t gr = r0 + row; if (gr >= RM) gr = RM - 1;
        const unsigned short* ga = A + (gr*16 + (size_t)(c ^ (row & 7)))*8;
        __builtin_amdgcn_global_load_lds((const unsigned int*)ga,
            (unsigned int*)&AsL[(i*256 + wid*64)*8], 16, 0, 0);
    }
    // 6 chunks of 64 qkv-cols
    for (int c6 = 0; c6 < 6; ++c6) {
        #pragma unroll
        for (int i = 0; i < 4; ++i) {
            int cid = i*256 + t;
            int nr = cid >> 4, c = cid & 15;
            const unsigned short* gb = WBq + ((size_t)(c6*64 + nr)*16 + (c ^ (nr & 7)))*8;
            __builtin_amdgcn_global_load_lds((const unsigned int*)gb,
                (unsigned int*)&BsL[(i*256 + wid*64)*8], 16, 0, 0);
        }
        __syncthreads();                 // stage drained (A too on first iter)
        f32x4 acc[4] = {};
        #pragma unroll
        for (int ks = 0; ks < 4; ++ks) {
            const int cA = ks*4 + kh;
            const int cn = wid*16 + rl;
            short8 bfr = *(const short8*)&BsL[cn*128 + ((cA ^ (cn & 7))*8)];
            #pragma unroll
            for (int i = 0; i < 4; ++i) {
                int row = i*16 + rl;
                short8 af = *(const short8*)&AsL[row*128 + ((cA ^ (row & 7))*8)];
                acc[i] = __builtin_amdgcn_mfma_f32_16x16x32_bf16(af, bfr, acc[i], 0, 0, 0);
            }
        }
        __syncthreads();                 // BsL reads done -> next stage safe
        // scatter into QKV head-major LDS
        const int col = c6*64 + wid*16 + rl;
        const int hd = col >> 3, d = col & 7;
        const float bs = bias[col];
        #pragma unroll
        for (int i = 0; i < 4; ++i)
            #pragma unroll
            for (int r = 0; r < 4; ++r) {
                int row = i*16 + rq*4 + r;
                QKV[(size_t)(hd*64 + row)*8 + d] = f2b(acc[i][r] + bs);
            }
    }
    if constexpr (L > 0) {
        // stage k0 slabs (16 heads x 63 rows) into BsL (dead after qkv)
        for (int idx = t; idx < 16*63; idx += 256) {
            int hd2 = idx / 63, j = idx - hd2*63;
            ushort8v u = *(const ushort8v*)&q0k0[(((size_t)(16 + hd2))*RM + r0 + j)*8];
            *(ushort8v*)&BsL[(hd2*63 + j)*8] = u;
        }
    }
    __syncthreads();                     // QKV (+k0 staging) visible
    if constexpr (L == 0) {
        // export q,k slabs rows 0..62 only (row 63 belongs to bn+1 -> must not write)
        for (int idx = t; idx < 32*63; idx += 256) {
            int hd2 = idx / 63, j = idx - hd2*63;
            ushort8v u = *(const ushort8v*)&QKV[(size_t)(hd2*64 + j)*8];
            *(ushort8v*)&q0k0out[((size_t)hd2*RM + r0 + j)*8] = u;
        }
    }
    // attention: wave wid handles heads wid*4 .. wid*4+3
    if (lane >= 63) return;
    const float scl  = scale[L];
    const float scl0 = (L > 0) ? scale[0] : 0.f;
    for (int hh = 0; hh < 4; ++hh) {
        const int hd = wid*4 + hh;
        float qr[8], q0r[8] = {};
        ushort8v qu = *(const ushort8v*)&QKV[(size_t)(hd*64 + lane)*8];
        #pragma unroll
        for (int d = 0; d < 8; ++d) qr[d] = b2f(qu[d]);
        if constexpr (L > 0) {
            ushort8v q0u = *(const ushort8v*)&q0k0[((size_t)hd*RM + r0 + lane)*8];
            #pragma unroll
            for (int d = 0; d < 8; ++d) q0r[d] = b2f(q0u[d]);
        }
        float sum = 0.f;
        float oa[8] = {};
        for (int j = 0; j < 63; ++j) {
            ushort8v ku = *(const ushort8v*)&QKV[(size_t)((16 + hd)*64 + j)*8];   // broadcast
            float s = 0.f;
            #pragma unroll
            for (int d = 0; d < 8; ++d) s += qr[d]*b2f(ku[d]);
            s *= scl;
            if constexpr (L > 0) {
                ushort8v k0u = *(const ushort8v*)&BsL[(hd*63 + j)*8];             // broadcast
                float s0 = 0.f;
                #pragma unroll
                for (int d = 0; d < 8; ++d) s0 += q0r[d]*b2f(k0u[d]);
                s += scl0 * s0;
            }
            float p = __expf(s);          // |s| <~ 3 by construction
            sum += p;
            ushort8v vu = *(const ushort8v*)&QKV[(size_t)((32 + hd)*64 + j)*8];   // broadcast
            #pragma unroll
            for (int d = 0; d < 8; ++d) oa[d] += p*b2f(vu[d]);
        }
        float inv = 1.f / sum;
        ushort8v u;
        #pragma unroll
        for (int d = 0; d < 8; ++d) u[d] = f2b(oa[d]*inv);
        *(ushort8v*)&ob[((size_t)hd*RM + r0 + lane)*8] = u;
    }
}

// ---------------- Fused FF v2 (BM=64, 80 KB LDS -> 2 blocks/CU) ----------------
__global__ __launch_bounds__(256) void ffused(
    const unsigned short* __restrict__ A, const unsigned short* __restrict__ W1,
    const float* __restrict__ b1, const unsigned short* __restrict__ W2,
    const float* __restrict__ b2, const unsigned short* __restrict__ Rsd,
    const float* __restrict__ snR,
    unsigned short* __restrict__ Cb, float* __restrict__ part)
{
    __shared__ __align__(16) char smem[81920];           // 80 KB exactly
    unsigned short* AsL = (unsigned short*)smem;          // 16 KB: A 64x128
    unsigned short* BsL = (unsigned short*)(smem + 16384);// 32 KB: W half 128x128
    unsigned short* G   = (unsigned short*)(smem + 49152);// 32 KB: gelu hidden 64x256
    float* sred = (float*)(smem + 49152);                 // aliases G (dead after ff2)
    float* qred = sred + 512;
    const int t = threadIdx.x;
    const int lane = t & 63, wid = t >> 6;
    const int wr = wid >> 1, wc = wid & 1;
    const int m0 = blockIdx.x * 64;
    const int kh = lane >> 4, rl = lane & 15;
    const int rq = lane >> 4;

    #pragma unroll
    for (int i = 0; i < 4; ++i) {
        int cid = i*256 + t;
        int row = cid >> 4, c = cid & 15;
        const unsigned short* ga = A + ((size_t)(m0+row)*16 + (c ^ (row & 7)))*8;
        __builtin_amdgcn_global_load_lds((const unsigned int*)ga,
            (unsigned int*)&AsL[(i*256 + wid*64)*8], 16, 0, 0);
    }
    #pragma unroll
    for (int i = 0; i < 8; ++i) {
        int cid = i*256 + t;
        int nr = cid >> 4, c = cid & 15;
        const unsigned short* gb = W1 + ((size_t)nr*16 + (c ^ (nr & 7)))*8;
        __builtin_amdgcn_global_load_lds((const unsigned int*)gb,
            (unsigned int*)&BsL[(i*256 + wid*64)*8], 16, 0, 0);
    }
    __syncthreads();
    for (int ib = 0; ib < 2; ++ib) {
        f32x4 acc[2][4] = {};
        #pragma unroll
        for (int ks = 0; ks < 4; ++ks) {
            const int cA = ks*4 + kh;
            short8 af[2], bfr[4];
            #pragma unroll
            for (int i = 0; i < 2; ++i) {
                int row = wr*32 + i*16 + rl;
                af[i] = *(const short8*)&AsL[row*128 + ((cA ^ (row & 7))*8)];
            }
            #pragma unroll
            for (int j = 0; j < 4; ++j) {
                int cn = wc*64 + j*16 + rl;
                bfr[j] = *(const short8*)&BsL[cn*128 + ((cA ^ (cn & 7))*8)];
            }
            #pragma unroll
            for (int i = 0; i < 2; ++i)
                #pragma unroll
                for (int j = 0; j < 4; ++j)
                    acc[i][j] = __builtin_amdgcn_mfma_f32_16x16x32_bf16(af[i], bfr[j], acc[i][j], 0, 0, 0);
        }
        __syncthreads();
        if (ib == 0) {
            #pragma unroll
            for (int i = 0; i < 8; ++i) {
                int cid = i*256 + t;
                int nr = cid >> 4, c = cid & 15;
                const unsigned short* gb = W1 + ((size_t)(128+nr)*16 + (c ^ (nr & 7)))*8;
                __builtin_amdgcn_global_load_lds((const unsigned int*)gb,
                    (unsigned int*)&BsL[(i*256 + wid*64)*8], 16, 0, 0);
            }
        }
        #pragma unroll
        for (int j = 0; j < 4; ++j) {
            const int col_l = wc*64 + j*16 + rl;
            const int colg = ib*128 + col_l;
            const float bs = b1[colg];
            const int cg = colg >> 3, bo2 = (colg & 7) << 1;
            #pragma unroll
            for (int i = 0; i < 2; ++i) {
                #pragma unroll
                for (int r = 0; r < 4; ++r) {
                    const int row_l = wr*32 + i*16 + rq*4 + r;
                    float v = gelu_f(acc[i][j][r] + bs);
                    *(unsigned short*)((char*)G + row_l*512 + (((cg ^ (row_l & 15)))<<4) + bo2) = f2b(v);
                }
            }
        }
        __syncthreads();
    }
    f32x4 acc2[2][4] = {};
    for (int kt = 0; kt < 2; ++kt) {
        #pragma unroll
        for (int i = 0; i < 8; ++i) {
            int cid = i*256 + t;
            int nr = cid >> 4, c = cid & 15;
            const unsigned short* gb = W2 + ((size_t)nr*32 + kt*16 + (c ^ (nr & 7)))*8;
            __builtin_amdgcn_global_load_lds((const unsigned int*)gb,
                (unsigned int*)&BsL[(i*256 + wid*64)*8], 16, 0, 0);
        }
        __syncthreads();
        #pragma unroll
        for (int ks = 0; ks < 4; ++ks) {
            const int cA = ks*4 + kh;
            short8 af[2], bfr[4];
            #pragma unroll
            for (int i = 0; i < 2; ++i) {
                int row = wr*32 + i*16 + rl;
                af[i] = *(const short8*)((const char*)G + row*512 + ((((kt*16 + cA) ^ (row & 15)))<<4));
            }
            #pragma unroll
            for (int j = 0; j < 4; ++j) {
                int cn = wc*64 + j*16 + rl;
                bfr[j] = *(const short8*)&BsL[cn*128 + ((cA ^ (cn & 7))*8)];
            }
            #pragma unroll
            for (int i = 0; i < 2; ++i)
                #pragma unroll
                for (int j = 0; j < 4; ++j)
                    acc2[i][j] = __builtin_amdgcn_mfma_f32_16x16x32_bf16(af[i], bfr[j], acc2[i][j], 0, 0, 0);
        }
        __syncthreads();
    }
    #pragma unroll
    for (int j = 0; j < 4; ++j) {
        const int col_l = wc*64 + j*16 + rl;
        const float bs = b2[col_l];
        const int chunk = col_l >> 3, bo2 = (col_l & 7) << 1;
        #pragma unroll
        for (int i = 0; i < 2; ++i) {
            #pragma unroll
            for (int r = 0; r < 4; ++r) {
                const int row_l = wr*32 + i*16 + rq*4 + r;
                *(unsigned short*)((char*)AsL + row_l*256 + ((chunk ^ (row_l & 15))<<4) + bo2)
                    = f2b(acc2[i][j][r] + bs);
            }
        }
    }
    __syncthreads();
    float sj[8] = {}, qj[8] = {};
    #pragma unroll
    for (int it = 0; it < 4; ++it) {
        const int row_l = it*16 + (t >> 4), c = t & 15;
        ushort8v u = *(const ushort8v*)((const char*)AsL + row_l*256 + ((c ^ (row_l & 15))<<4));
        const size_t gbase = (size_t)(m0 + row_l)*128 + c*8;
        ushort8v rs = *(const ushort8v*)&Rsd[gbase];
        ushort8v o8;
        #pragma unroll
        for (int jj = 0; jj < 8; ++jj) {
            float v = b2f(u[jj]) + b2f(rs[jj])*snR[c*8+jj] + snR[128 + c*8 + jj];
            sj[jj] += v; qj[jj] += v*v;
            o8[jj] = f2b(v);
        }
        *(ushort8v*)&Cb[gbase] = o8;
    }
    #pragma unroll
    for (int jj = 0; jj < 8; ++jj) {
        sj[jj] += __shfl_xor(sj[jj], 16); qj[jj] += __shfl_xor(qj[jj], 16);
        sj[jj] += __shfl_xor(sj[jj], 32); qj[jj] += __shfl_xor(qj[jj], 32);
    }
    if ((lane >> 4) == 0) {
        #pragma unroll
        for (int jj = 0; jj < 8; ++jj) {
            sred[wid*128 + lane*8 + jj] = sj[jj];
            qred[wid*128 + lane*8 + jj] = qj[jj];
        }
    }
    __syncthreads();
    if (t < 128) {
        const int c2 = t >> 3, jj = t & 7;
        float s = sred[0*128 + c2*8 + jj] + sred[1*128 + c2*8 + jj]
                + sred[2*128 + c2*8 + jj] + sred[3*128 + c2*8 + jj];
        float q = qred[0*128 + c2*8 + jj] + qred[1*128 + c2*8 + jj]
                + qred[2*128 + c2*8 + jj] + qred[3*128 + c2*8 + jj];
        part[(size_t)blockIdx.x*256 + t]       = s;
        part[(size_t)blockIdx.x*256 + 128 + t] = q;
    }
}

// ---------------- BN stats finalize (1008 block-partials) ----------------
__global__ __launch_bounds__(256) void bnred(const float* __restrict__ part,
    const float* __restrict__ g, const float* __restrict__ b, float* __restrict__ sn)
{
    const int c = blockIdx.x, t = threadIdx.x;
    float s = 0.f, q = 0.f;
    for (int bid = t; bid < 1008; bid += 256) {
        s += part[(size_t)bid*256 + c];
        q += part[(size_t)bid*256 + 128 + c];
    }
    __shared__ float ls[256], lq[256];
    ls[t] = s; lq[t] = q;
    __syncthreads();
    for (int o = 128; o > 0; o >>= 1) {
        if (t < o) { ls[t] += ls[t+o]; lq[t] += lq[t+o]; }
        __syncthreads();
    }
    if (t == 0) {
        const float invM = 1.f / (float)RM;
        float mean = ls[0] * invM;
        float var  = fmaxf(lq[0]*invM - mean*mean, 0.f);
        float sc = g[c] * rsqrtf(var + 1e-5f);
        sn[c]       = sc;
        sn[128 + c] = b[c] - mean*sc;
    }
}

// ---------------- Weight fold ----------------
__global__ __launch_bounds__(256) void wfold(const unsigned short* __restrict__ WBs,
    const float* __restrict__ sn, const float* __restrict__ bsrc,
    unsigned short* __restrict__ WBd, float* __restrict__ bdst)
{
    const int t = threadIdx.x, wv = t >> 6, lane = t & 63;
    const int n = blockIdx.x*4 + wv;
    float w1 = b2f(WBs[(size_t)n*128 + lane]);
    float w2 = b2f(WBs[(size_t)n*128 + 64 + lane]);
    WBd[(size_t)n*128 + lane]      = f2b(sn[lane]*w1);
    WBd[(size_t)n*128 + 64 + lane] = f2b(sn[64+lane]*w2);
    float bacc = sn[128+lane]*w1 + sn[192+lane]*w2;
    #pragma unroll
    for (int msk = 1; msk < 64; msk <<= 1) bacc += __shfl_xor(bacc, msk);
    if (lane == 0) bdst[n] = bsrc[n] + bacc;
}

// ---------------- Head prep: blocks 0..62 fold weights (p-major), 63..158 fold bias ----------------
__global__ __launch_bounds__(256) void hprep(
    const float* __restrict__ hw, const float* __restrict__ hb,
    const float* __restrict__ sn,
    unsigned short* __restrict__ hwTf, float* __restrict__ hbf)
{
    const int t = threadIdx.x;
    if (blockIdx.x < 63) {
        const int p = blockIdx.x;
        for (int idx = t; idx < 16384; idx += 256) {
            int n = idx >> 7, d = idx & 127;
            unsigned short w = 0;
            if (n < 96) w = f2b(sn[d] * hw[(size_t)(d*63 + p)*96 + n]);
            hwTf[((size_t)p*128 + n)*128 + d] = w;
        }
    } else {
        const int n = blockIdx.x - 63;   // 0..95
        float acc = 0.f;
        for (int k = t; k < 8064; k += 256) {
            int d = (int)(((unsigned)k * 33289u) >> 21);
            acc += sn[128 + d] * hw[(size_t)k*96 + n];
        }
        __shared__ float ls[256];
        ls[t] = acc;
        __syncthreads();
        for (int o = 128; o > 0; o >>= 1) { if (t < o) ls[t] += ls[t+o]; __syncthreads(); }
        if (t == 0) hbf[n] = hb[n] + ls[0];
    }
}

// ---------------- Head MFMA GEMM: p-major 63-way K-split, coalesced A ----------------
__global__ __launch_bounds__(256) void mhead(
    const unsigned short* __restrict__ A, const unsigned short* __restrict__ BW,
    float* __restrict__ part)
{
    __shared__ __align__(16) unsigned short AsL[128*128];
    __shared__ __align__(16) unsigned short BsL[128*128];
    const int t = threadIdx.x;
    const int lane = t & 63, wid = t >> 6;
    const int wr = wid >> 1, wc = wid & 1;
    const int m0 = blockIdx.x * 128;
    const int p  = blockIdx.y;
    #pragma unroll
    for (int i = 0; i < 8; ++i) {
        int cid = i*256 + t;
        int row = cid >> 4, c = cid & 15;
        const unsigned short* ga = A + ((size_t)(m0+row)*63 + p)*128 + ((c ^ (row & 7))*8);
        __builtin_amdgcn_global_load_lds((const unsigned int*)ga,
            (unsigned int*)&AsL[(i*256 + wid*64)*8], 16, 0, 0);
    }
    #pragma unroll
    for (int i = 0; i < 8; ++i) {
        int cid = i*256 + t;
        int nr = cid >> 4, c = cid & 15;
        const unsigned short* gb = BW + ((size_t)p*128 + nr)*128 + ((c ^ (nr & 7))*8);
        __builtin_amdgcn_global_load_lds((const unsigned int*)gb,
            (unsigned int*)&BsL[(i*256 + wid*64)*8], 16, 0, 0);
    }
    __syncthreads();
    const int kh = lane >> 4, rl = lane & 15;
    f32x4 acc[4][3] = {};
    #pragma unroll
    for (int kq = 0; kq < 4; ++kq) {
        const int cA = kq*4 + kh;
        short8 af[4], bfr[3];
        #pragma unroll
        for (int i = 0; i < 4; ++i) {
            int row = wr*64 + i*16 + rl;
            af[i] = *(const short8*)&AsL[row*128 + ((cA ^ (row & 7))*8)];
        }
        #pragma unroll
        for (int j = 0; j < 3; ++j) {
            int cn = wc*48 + j*16 + rl;
            bfr[j] = *(const short8*)&BsL[cn*128 + ((cA ^ (cn & 7))*8)];
        }
        #pragma unroll
        for (int i = 0; i < 4; ++i)
            #pragma unroll
            for (int j = 0; j < 3; ++j)
                acc[i][j] = __builtin_amdgcn_mfma_f32_16x16x32_bf16(af[i], bfr[j], acc[i][j], 0, 0, 0);
    }
    const int rl2 = lane & 15, rq = lane >> 4;
    #pragma unroll
    for (int j = 0; j < 3; ++j) {
        const int col = wc*48 + j*16 + rl2;
        #pragma unroll
        for (int i = 0; i < 4; ++i) {
            const int rbase = m0 + wr*64 + i*16 + rq*4;
            #pragma unroll
            for (int r = 0; r < 4; ++r)
                part[((size_t)p*1024 + rbase + r)*96 + col] = acc[i][j][r];
        }
    }
}

__global__ __launch_bounds__(256) void head_reduce(const float* __restrict__ part,
    const float* __restrict__ hbf, float* __restrict__ out)
{
    int idx = blockIdx.x*256 + threadIdx.x;
    float s = hbf[idx % 96];
    #pragma unroll
    for (int blk = 0; blk < 63; ++blk) s += part[(size_t)blk*98304 + idx];
    out[idx] = s;
}

extern "C" void kernel_launch(void* const* d_in, const int* in_sizes, int n_in,
                              void* d_out, int out_size, void* d_ws, size_t ws_size,
                              hipStream_t stream) {
    const float* x    = (const float*)d_in[0];
    const float* adj  = (const float*)d_in[1];
    const float* sw   = (const float*)d_in[2];
    const float* sb   = (const float*)d_in[3];
    const float* mw   = (const float*)d_in[4];
    const float* mb   = (const float*)d_in[5];
    const float* Wp   = (const float*)d_in[6];
    const float* bp   = (const float*)d_in[7];
    const float* Wpos = (const float*)d_in[8];
    const float* Wq   = (const float*)d_in[9];
    const float* bq   = (const float*)d_in[10];
    const float* Wk   = (const float*)d_in[11];
    const float* bk   = (const float*)d_in[12];
    const float* Wv   = (const float*)d_in[13];
    const float* bv   = (const float*)d_in[14];
    const float* Wo   = (const float*)d_in[15];
    const float* bo   = (const float*)d_in[16];
    const float* scale= (const float*)d_in[17];
    const float* bn1g = (const float*)d_in[18];
    const float* bn1b = (const float*)d_in[19];
    const float* fw1  = (const float*)d_in[20];
    const float* fb1  = (const float*)d_in[21];
    const float* fw2  = (const float*)d_in[22];
    const float* fb2  = (const float*)d_in[23];
    const float* bn2g = (const float*)d_in[24];
    const float* bn2b = (const float*)d_in[25];
    const float* hw   = (const float*)d_in[26];
    const float* hb   = (const float*)d_in[27];
    float* out = (float*)d_out;

    // ---- workspace layout ----
    float* y     = (float*)d_ws;             // 524288
    float* part  = y     + 524288;           // 258048 (1008*256 BN partials)
    float* snorm = part  + 258048;           // 1024
    float* bcat  = snorm + 1024;             // 768
    float* bfold = bcat  + 768;              // 1024
    float* hbf   = bfold + 1024;             // 128
    float* hpart = hbf   + 128;              // 6193152 (63*1024*96)
    unsigned short* srcb = (unsigned short*)(hpart + 6193152);  // RM*128 bf16
    unsigned short* t1b  = srcb + 8257536;
    unsigned short* t2b  = t1b  + 8257536;
    unsigned short* o_bf = t2b  + 8257536;   // [16][RM][8] bf16
    unsigned short* q0k0 = o_bf + 8257536;   // [32][RM][8] bf16 (layer-0 q,k)
    unsigned short* WB   = q0k0 + 16515072;  // 262144
    unsigned short* WF   = WB   + 262144;    // ff1_0 32768, ff1_1 32768, qkv1 49152
    unsigned short* hwTf = WF   + 131072;    // 63*128*128 = 1032192

    dgcn_kernel<<<4864, 256, 0, stream>>>(x, adj, sw, sb, mw, mb, y,
        Wq, Wk, Wv, Wo, fw1, fw2, bq, bk, bv, WB, bcat);
    patch_kernel<<<1024, 256, 0, stream>>>(y, Wp, bp, Wpos, srcb);

    // ---------------- layer 0 ----------------
    qkattn<0><<<1024, 256, 0, stream>>>(srcb, WB, bcat, scale, nullptr, q0k0, o_bf);
    mgemm<0,2,1,true,true,1,128><<<1008, 256, 0, stream>>>(o_bf, WB + 49152, bo, srcb, nullptr, t1b, part);
    bnred<<<128, 256, 0, stream>>>(part, bn1g, bn1b, snorm);                       // snorm0 = BN1 l0
    wfold<<<64, 256, 0, stream>>>(WB + 65536, snorm, fb1, WF, bfold);              // ff1 l0
    ffused<<<1008, 256, 0, stream>>>(t1b, WF, bfold, WB + 98304, fb2, t1b, snorm, t2b, part);
    bnred<<<128, 256, 0, stream>>>(part, bn2g, bn2b, snorm + 256);                 // snorm1 = BN2 l0
    wfold<<<96, 256, 0, stream>>>(WB + 131072, snorm + 256, bcat + 384, WF + 65536, bfold + 512); // qkv l1

    // ---------------- layer 1 ----------------
    qkattn<1><<<1024, 256, 0, stream>>>(t2b, WF + 65536, bfold + 512, scale, q0k0, nullptr, o_bf);
    mgemm<0,2,2,true,true,1,128><<<1008, 256, 0, stream>>>(o_bf, WB + 131072 + 49152, bo + 128, t2b, snorm + 256, t1b, part);
    bnred<<<128, 256, 0, stream>>>(part, bn1g + 128, bn1b + 128, snorm + 512);     // snorm2 = BN1 l1
    wfold<<<64, 256, 0, stream>>>(WB + 131072 + 65536, snorm + 512, fb1 + 256, WF + 32768, bfold + 256);
    ffused<<<1008, 256, 0, stream>>>(t1b, WF + 32768, bfold + 256, WB + 131072 + 98304, fb2 + 128, t1b, snorm + 512, t2b, part);
    bnred<<<128, 256, 0, stream>>>(part, bn2g + 128, bn2b + 128, snorm + 768);     // snorm3 = BN2 l1

    // ---------------- head (MFMA, BN folded; p-major K-split) ----------------
    hprep<<<159, 256, 0, stream>>>(hw, hb, snorm + 768, hwTf, hbf);
    mhead<<<dim3(8,63), 256, 0, stream>>>(t2b, hwTf, hpart);
    head_reduce<<<384, 256, 0, stream>>>(hpart, hbf, out);
}

// Round 15
// 372.542 us; speedup vs baseline: 1.1744x; 1.1744x over previous
//
#include <hip/hip_runtime.h>
#include <hip/hip_bf16.h>
#include <math.h>

// Problem constants
#define RM 64512            // B*N*PN = 1024*63 rows through the transformer
// B=8 N=128 L=512 PN=63 PL=16 ST=8 DM=128 H=16 DFF=256 NL=2 DG=8 MP=3 TW=96

typedef short short8 __attribute__((ext_vector_type(8)));
typedef float f32x4 __attribute__((ext_vector_type(4)));
typedef unsigned short ushort4v __attribute__((ext_vector_type(4)));
typedef unsigned short ushort8v __attribute__((ext_vector_type(8)));

__device__ __forceinline__ float gelu_f(float v) {
    return 0.5f * v * (1.0f + erff(v * 0.70710678118654752f));
}
__device__ __forceinline__ float b2f(unsigned short u) {
    unsigned int x = ((unsigned int)u) << 16;
    return __builtin_bit_cast(float, x);
}
__device__ __forceinline__ unsigned short f2b(float f) {
    __hip_bfloat16 h = __float2bfloat16(f);   // RNE
    return __builtin_bit_cast(unsigned short, h);
}

// ---------------- Fused DGCN v3 + weight prep (blocks >= 4096) ----------------
__global__ __launch_bounds__(256) void dgcn_kernel(
    const float* __restrict__ x, const float* __restrict__ adj,
    const float* __restrict__ sw, const float* __restrict__ sb,
    const float* __restrict__ mw, const float* __restrict__ mb,
    float* __restrict__ y,
    const float* __restrict__ Wq, const float* __restrict__ Wk, const float* __restrict__ Wv,
    const float* __restrict__ Wo, const float* __restrict__ fw1, const float* __restrict__ fw2,
    const float* __restrict__ bq, const float* __restrict__ bk, const float* __restrict__ bv,
    unsigned short* __restrict__ WB, float* __restrict__ bcat)
{
    if (blockIdx.x >= 4096) {
        const int wb = blockIdx.x - 4096;
        const int id = wb / 64, bx = wb % 64;
        const int l = id / 6, mat = id % 6;
        const float* src; int K, N; size_t off = (size_t)l * 131072;
        switch (mat) {
            case 0: src = Wq  + l*16384; K = 128; N = 128; off += 0;      break;
            case 1: src = Wk  + l*16384; K = 128; N = 128; off += 16384;  break;
            case 2: src = Wv  + l*16384; K = 128; N = 128; off += 32768;  break;
            case 3: src = Wo  + l*16384; K = 128; N = 128; off += 49152;  break;
            case 4: src = fw1 + l*32768; K = 128; N = 256; off += 65536;  break;
            default:src = fw2 + l*32768; K = 256; N = 128; off += 98304;  break;
        }
        const int total = K * N;
        const int ksh = (K == 256) ? 8 : 7;
        for (int idx = bx*256 + threadIdx.x; idx < total; idx += 64*256) {
            int n = idx >> ksh, k = idx & (K - 1);
            WB[off + idx] = f2b(src[(size_t)k*N + n]);
        }
        if (id == 0 && bx == 0) {
            for (int idx = threadIdx.x; idx < 768; idx += 256) {
                int ll = idx / 384, j = idx % 384;
                float vv;
                if (j < 128)      vv = bq[ll*128 + j];
                else if (j < 256) vv = bk[ll*128 + j - 128];
                else              vv = bv[ll*128 + j - 256];
                bcat[idx] = vv;
            }
        }
        return;
    }
    __shared__ __align__(16) unsigned short ET[128*128];  // 32 KB
    __shared__ __align__(16) unsigned short hT[16*128];   // 4 KB
    __shared__ float red[256];
    __shared__ float iv[128];
    __shared__ float xc[128];
    __shared__ float yac[128];
    const int bid = blockIdx.x;            // b*512 + s
    const int b = bid >> 9, s = bid & 511;
    const int t = threadIdx.x;
    const int lane = t & 63, wid = t >> 6;
    const float* ap = adj + (size_t)bid * 16384;

    if (t < 128) xc[t] = x[((size_t)b*128 + t)*512 + s];

    // Phase 1: exp + transpose-write (swizzled) + colsum partials
    {
        const int m = t & 127, ng = t >> 7;
        float sm = 0.f;
        for (int p = 0; p < 16; ++p) {
            const int n0 = p*8 + ng*4;
            float e0 = __expf(ap[(size_t)(n0+0)*128 + m]);
            float e1 = __expf(ap[(size_t)(n0+1)*128 + m]);
            float e2 = __expf(ap[(size_t)(n0+2)*128 + m]);
            float e3 = __expf(ap[(size_t)(n0+3)*128 + m]);
            sm += e0 + e1 + e2 + e3;
            ushort4v u4; u4[0]=f2b(e0); u4[1]=f2b(e1); u4[2]=f2b(e2); u4[3]=f2b(e3);
            *(ushort4v*)((char*)ET + m*256 + (((n0>>3) ^ (m & 15))*16) + (n0 & 7)*2) = u4;
        }
        red[ng*128 + m] = sm;
        *(ushort4v*)&hT[8*128 + t*4] = (ushort4v){0,0,0,0};
    }
    __syncthreads();
    if (t < 128) iv[t] = 1.f / (red[t] + red[128 + t]);
    // Phase 2: h0 + y0 + hT rows 0..7
    if (t < 128) {
        const int m = t;
        const float xm = xc[m];
        float yp = 0.f;
        #pragma unroll
        for (int c = 0; c < 8; ++c) {
            float h = xm*sw[c] + sb[c];
            yp += h*mw[c];
            *(unsigned short*)((char*)hT + c*256 + ((((m>>3) ^ c))*16) + (m & 7)*2) = f2b(h);
        }
        yac[m] = yp;
    }
    __syncthreads();

    // Phase 3: 3 MFMA propagation steps. Wave wid owns m-tiles {2wid, 2wid+1}.
    const int rl = lane & 15, kh = lane >> 4;
    short8 af[2][4];
    float xr[2][4], ivr[2][4];
    #pragma unroll
    for (int ti = 0; ti < 2; ++ti) {
        const int mrow = (wid*2 + ti)*16 + rl;
        #pragma unroll
        for (int ks = 0; ks < 4; ++ks) {
            const int ch = (ks*4 + kh) ^ (mrow & 15);
            af[ti][ks] = *(const short8*)((const char*)ET + mrow*256 + ch*16);
        }
        #pragma unroll
        for (int r = 0; r < 4; ++r) {
            const int m = (wid*2 + ti)*16 + kh*4 + r;
            xr[ti][r]  = 0.05f * xc[m];
            ivr[ti][r] = 0.95f * iv[m];
        }
    }
    float yl[2][4] = {};
    #pragma unroll
    for (int step = 1; step <= 3; ++step) {
        short8 bfr[4];
        #pragma unroll
        for (int ks = 0; ks < 4; ++ks) {
            const int ch = (ks*4 + kh) ^ rl;
            bfr[ks] = *(const short8*)((const char*)hT + rl*256 + ch*16);
        }
        f32x4 acc[2] = {};
        #pragma unroll
        for (int ti = 0; ti < 2; ++ti)
            #pragma unroll
            for (int ks = 0; ks < 4; ++ks)
                acc[ti] = __builtin_amdgcn_mfma_f32_16x16x32_bf16(af[ti][ks], bfr[ks], acc[ti], 0, 0, 0);
        __syncthreads();
        const float mwc = (rl < 8) ? mw[step*8 + rl] : 0.f;
        #pragma unroll
        for (int ti = 0; ti < 2; ++ti) {
            const int m0 = (wid*2 + ti)*16 + kh*4;
            ushort4v hw4;
            float hnew[4];
            #pragma unroll
            for (int r = 0; r < 4; ++r) {
                float v = xr[ti][r] + ivr[ti][r]*acc[ti][r];
                hnew[r] = v;
                hw4[r] = f2b(v);
            }
            *(ushort4v*)((char*)hT + rl*256 + (((m0>>3) ^ rl)*16) + (m0 & 7)*2) = hw4;
            #pragma unroll
            for (int r = 0; r < 4; ++r) {
                float vv = hnew[r]*mwc;
                vv += __shfl_xor(vv, 1);
                vv += __shfl_xor(vv, 2);
                vv += __shfl_xor(vv, 4);
                vv += __shfl_xor(vv, 8);
                yl[ti][r] += vv;
            }
        }
        __syncthreads();
    }
    if (rl == 0) {
        #pragma unroll
        for (int ti = 0; ti < 2; ++ti)
            #pragma unroll
            for (int r = 0; r < 4; ++r)
                yac[(wid*2 + ti)*16 + kh*4 + r] += yl[ti][r];
    }
    __syncthreads();
    if (t < 128) y[((size_t)b*128 + t)*512 + s] = yac[t] + mb[0];
}

// ---------------- Patch embedding: srcb = bf16(z @ W_P + b_P + W_pos) ----------------
__global__ __launch_bounds__(256) void patch_kernel(
    const float* __restrict__ y, const float* __restrict__ Wp, const float* __restrict__ bp,
    const float* __restrict__ Wpos, unsigned short* __restrict__ srcb)
{
    __shared__ float ys[512];
    __shared__ float wps[16*128];
    const int bn = blockIdx.x;
    const int t = threadIdx.x;
    ys[t]       = y[(size_t)bn*512 + t];
    ys[t + 256] = y[(size_t)bn*512 + t + 256];
    #pragma unroll
    for (int r = 0; r < 8; ++r) wps[t + r*256] = Wp[t + r*256];
    __syncthreads();
    for (int cu = t; cu < 1008; cu += 256) {
        int p = cu >> 4, d0 = (cu & 15) * 8;
        float o[8];
        #pragma unroll
        for (int j = 0; j < 8; ++j) o[j] = bp[d0+j] + Wpos[p*128 + d0 + j];
        #pragma unroll
        for (int tt = 0; tt < 16; ++tt) {
            float a = ys[p*8 + tt];
            #pragma unroll
            for (int j = 0; j < 8; ++j) o[j] += a * wps[tt*128 + d0 + j];
        }
        size_t row = (size_t)bn*63 + p;
        ushort8v u;
        #pragma unroll
        for (int j = 0; j < 8; ++j) u[j] = f2b(o[j]);
        *(ushort8v*)&srcb[row*128 + d0] = u;
    }
}

// ---------------- bf16 MFMA GEMM, BM=64 rows (52 KB LDS -> 3 blocks/CU) ----------------
template<int ACT, int OM, int RESMODE, bool STATS, bool AHM, int NB, int KK>
__global__ __launch_bounds__(256) void mgemm(
    const unsigned short* __restrict__ A, const unsigned short* __restrict__ WB,
    const float* __restrict__ bias, const unsigned short* __restrict__ Rsd,
    const float* __restrict__ snR,
    unsigned short* __restrict__ Cb,
    float* __restrict__ part)
{
    constexpr int NTOT = NB * 128;
    constexpr int kch = KK >> 3;
    constexpr int KT = KK >> 7;
    __shared__ __align__(16) unsigned short AsL[64*128];   // 16 KB
    __shared__ __align__(16) unsigned short BsL[128*128];  // 32 KB
    __shared__ float sred[4][16][8], qred[4][16][8];
    const int t = threadIdx.x;
    const int lane = t & 63, wid = t >> 6;
    const int wr = wid >> 1, wc = wid & 1;
    const int m0 = blockIdx.x * 64;
    const int kh = lane >> 4, rl = lane & 15;
    const int rq = lane >> 4;
    float sj[8] = {}, qj[8] = {};

    for (int ib = 0; ib < NB; ++ib) {
        f32x4 acc[2][4] = {};
        for (int kt = 0; kt < KT; ++kt) {
            if (ib == 0 || KT > 1) {
                #pragma unroll
                for (int i = 0; i < 4; ++i) {
                    int cid = i*256 + t;
                    const unsigned short* ga;
                    if constexpr (AHM) {
                        int hd2 = cid >> 6, row = cid & 63;
                        ga = A + ((size_t)hd2*RM + (m0+row))*8;
                    } else {
                        int row = cid >> 4, c = cid & 15;
                        int c_g = c ^ (row & 7);
                        ga = A + ((size_t)(m0+row)*kch + kt*16 + c_g)*8;
                    }
                    __builtin_amdgcn_global_load_lds((const unsigned int*)ga,
                        (unsigned int*)&AsL[(i*256 + wid*64)*8], 16, 0, 0);
                }
            }
            #pragma unroll
            for (int i = 0; i < 8; ++i) {
                int cid = i*256 + t;
                int nr = cid >> 4, c = cid & 15;
                const unsigned short* gb = WB + (size_t)ib*128*KK
                    + ((size_t)nr*kch + kt*16 + (c ^ (nr & 7)))*8;
                __builtin_amdgcn_global_load_lds((const unsigned int*)gb,
                    (unsigned int*)&BsL[(i*256 + wid*64)*8], 16, 0, 0);
            }
            __syncthreads();
            #pragma unroll
            for (int ks = 0; ks < 4; ++ks) {
                const int cA = ks*4 + kh;
                short8 af[2], bfr[4];
                #pragma unroll
                for (int i = 0; i < 2; ++i) {
                    int row = wr*32 + i*16 + rl;
                    if constexpr (AHM) af[i] = *(const short8*)&AsL[(cA*64 + row)*8];
                    else               af[i] = *(const short8*)&AsL[row*128 + ((cA ^ (row & 7))*8)];
                }
                #pragma unroll
                for (int j = 0; j < 4; ++j) {
                    int cn = wc*64 + j*16 + rl;
                    bfr[j] = *(const short8*)&BsL[cn*128 + ((cA ^ (cn & 7))*8)];
                }
                #pragma unroll
                for (int i = 0; i < 2; ++i)
                    #pragma unroll
                    for (int j = 0; j < 4; ++j)
                        acc[i][j] = __builtin_amdgcn_mfma_f32_16x16x32_bf16(af[i], bfr[j], acc[i][j], 0, 0, 0);
            }
            __syncthreads();
        }
        // E1: repack 64x128 tile into BsL (chunk^row15 swizzle)
        #pragma unroll
        for (int j = 0; j < 4; ++j) {
            const int col_l = wc*64 + j*16 + rl;
            const float bs = bias[ib*128 + col_l];
            const int chunk = col_l >> 3, bo2 = (col_l & 7) << 1;
            #pragma unroll
            for (int i = 0; i < 2; ++i) {
                #pragma unroll
                for (int r = 0; r < 4; ++r) {
                    const int row_l = wr*32 + i*16 + rq*4 + r;
                    float v = acc[i][j][r] + bs;
                    if constexpr (ACT == 1) v = gelu_f(v);
                    *(unsigned short*)((char*)BsL + row_l*256 + ((chunk ^ (row_l & 15))<<4) + bo2) = f2b(v);
                }
            }
        }
        __syncthreads();
        // E2: coalesced read-out
        if constexpr (OM == 1) {
            #pragma unroll
            for (int it = 0; it < 4; ++it) {
                int cid = it*256 + t;
                int row_l = cid & 63, hd_l = cid >> 6;
                ushort8v u = *(const ushort8v*)((const char*)BsL + row_l*256 + ((hd_l ^ (row_l & 15))<<4));
                *(ushort8v*)&Cb[(((size_t)(ib*16 + hd_l))*RM + m0 + row_l)*8] = u;
            }
        } else {
            #pragma unroll
            for (int it = 0; it < 4; ++it) {
                const int row_l = it*16 + (t >> 4), c = t & 15;
                ushort8v u = *(const ushort8v*)((const char*)BsL + row_l*256 + ((c ^ (row_l & 15))<<4));
                const size_t gbase = (size_t)(m0 + row_l)*NTOT + ib*128 + c*8;
                ushort8v rs = {};
                if constexpr (RESMODE != 0) rs = *(const ushort8v*)&Rsd[gbase];
                ushort8v o8;
                #pragma unroll
                for (int jj = 0; jj < 8; ++jj) {
                    float v = b2f(u[jj]);
                    if constexpr (RESMODE == 1) v += b2f(rs[jj]);
                    if constexpr (RESMODE == 2) v += b2f(rs[jj])*snR[c*8+jj] + snR[128 + c*8 + jj];
                    if constexpr (STATS) { sj[jj] += v; qj[jj] += v*v; }
                    o8[jj] = f2b(v);
                }
                *(ushort8v*)&Cb[gbase] = o8;
            }
        }
        __syncthreads();
    }
    if constexpr (STATS) {
        #pragma unroll
        for (int jj = 0; jj < 8; ++jj) {
            sj[jj] += __shfl_xor(sj[jj], 16); qj[jj] += __shfl_xor(qj[jj], 16);
            sj[jj] += __shfl_xor(sj[jj], 32); qj[jj] += __shfl_xor(qj[jj], 32);
        }
        if ((lane >> 4) == 0) {
            #pragma unroll
            for (int jj = 0; jj < 8; ++jj) {
                sred[wid][lane][jj] = sj[jj];
                qred[wid][lane][jj] = qj[jj];
            }
        }
        __syncthreads();
        if (t < 128) {
            const int c2 = t >> 3, jj = t & 7;
            float s = sred[0][c2][jj] + sred[1][c2][jj] + sred[2][c2][jj] + sred[3][c2][jj];
            float q = qred[0][c2][jj] + qred[1][c2][jj] + qred[2][c2][jj] + qred[3][c2][jj];
            part[(size_t)blockIdx.x*256 + t]       = s;
            part[(size_t)blockIdx.x*256 + 128 + t] = q;
        }
    }
}

// ---------------- Fused FF v2 (BM=64, 80 KB LDS -> 2 blocks/CU) ----------------
__global__ __launch_bounds__(256) void ffused(
    const unsigned short* __restrict__ A, const unsigned short* __restrict__ W1,
    const float* __restrict__ b1, const unsigned short* __restrict__ W2,
    const float* __restrict__ b2, const unsigned short* __restrict__ Rsd,
    const float* __restrict__ snR,
    unsigned short* __restrict__ Cb, float* __restrict__ part)
{
    __shared__ __align__(16) char smem[81920];           // 80 KB exactly
    unsigned short* AsL = (unsigned short*)smem;          // 16 KB: A 64x128
    unsigned short* BsL = (unsigned short*)(smem + 16384);// 32 KB: W half 128x128
    unsigned short* G   = (unsigned short*)(smem + 49152);// 32 KB: gelu hidden 64x256
    float* sred = (float*)(smem + 49152);                 // aliases G (dead after ff2)
    float* qred = sred + 512;
    const int t = threadIdx.x;
    const int lane = t & 63, wid = t >> 6;
    const int wr = wid >> 1, wc = wid & 1;
    const int m0 = blockIdx.x * 64;
    const int kh = lane >> 4, rl = lane & 15;
    const int rq = lane >> 4;

    #pragma unroll
    for (int i = 0; i < 4; ++i) {
        int cid = i*256 + t;
        int row = cid >> 4, c = cid & 15;
        const unsigned short* ga = A + ((size_t)(m0+row)*16 + (c ^ (row & 7)))*8;
        __builtin_amdgcn_global_load_lds((const unsigned int*)ga,
            (unsigned int*)&AsL[(i*256 + wid*64)*8], 16, 0, 0);
    }
    #pragma unroll
    for (int i = 0; i < 8; ++i) {
        int cid = i*256 + t;
        int nr = cid >> 4, c = cid & 15;
        const unsigned short* gb = W1 + ((size_t)nr*16 + (c ^ (nr & 7)))*8;
        __builtin_amdgcn_global_load_lds((const unsigned int*)gb,
            (unsigned int*)&BsL[(i*256 + wid*64)*8], 16, 0, 0);
    }
    __syncthreads();
    for (int ib = 0; ib < 2; ++ib) {
        f32x4 acc[2][4] = {};
        #pragma unroll
        for (int ks = 0; ks < 4; ++ks) {
            const int cA = ks*4 + kh;
            short8 af[2], bfr[4];
            #pragma unroll
            for (int i = 0; i < 2; ++i) {
                int row = wr*32 + i*16 + rl;
                af[i] = *(const short8*)&AsL[row*128 + ((cA ^ (row & 7))*8)];
            }
            #pragma unroll
            for (int j = 0; j < 4; ++j) {
                int cn = wc*64 + j*16 + rl;
                bfr[j] = *(const short8*)&BsL[cn*128 + ((cA ^ (cn & 7))*8)];
            }
            #pragma unroll
            for (int i = 0; i < 2; ++i)
                #pragma unroll
                for (int j = 0; j < 4; ++j)
                    acc[i][j] = __builtin_amdgcn_mfma_f32_16x16x32_bf16(af[i], bfr[j], acc[i][j], 0, 0, 0);
        }
        __syncthreads();
        if (ib == 0) {
            #pragma unroll
            for (int i = 0; i < 8; ++i) {
                int cid = i*256 + t;
                int nr = cid >> 4, c = cid & 15;
                const unsigned short* gb = W1 + ((size_t)(128+nr)*16 + (c ^ (nr & 7)))*8;
                __builtin_amdgcn_global_load_lds((const unsigned int*)gb,
                    (unsigned int*)&BsL[(i*256 + wid*64)*8], 16, 0, 0);
            }
        }
        #pragma unroll
        for (int j = 0; j < 4; ++j) {
            const int col_l = wc*64 + j*16 + rl;
            const int colg = ib*128 + col_l;
            const float bs = b1[colg];
            const int cg = colg >> 3, bo2 = (colg & 7) << 1;
            #pragma unroll
            for (int i = 0; i < 2; ++i) {
                #pragma unroll
                for (int r = 0; r < 4; ++r) {
                    const int row_l = wr*32 + i*16 + rq*4 + r;
                    float v = gelu_f(acc[i][j][r] + bs);
                    *(unsigned short*)((char*)G + row_l*512 + (((cg ^ (row_l & 15)))<<4) + bo2) = f2b(v);
                }
            }
        }
        __syncthreads();
    }
    f32x4 acc2[2][4] = {};
    for (int kt = 0; kt < 2; ++kt) {
        #pragma unroll
        for (int i = 0; i < 8; ++i) {
            int cid = i*256 + t;
            int nr = cid >> 4, c = cid & 15;
            const unsigned short* gb = W2 + ((size_t)nr*32 + kt*16 + (c ^ (nr & 7)))*8;
            __builtin_amdgcn_global_load_lds((const unsigned int*)gb,
                (unsigned int*)&BsL[(i*256 + wid*64)*8], 16, 0, 0);
        }
        __syncthreads();
        #pragma unroll
        for (int ks = 0; ks < 4; ++ks) {
            const int cA = ks*4 + kh;
            short8 af[2], bfr[4];
            #pragma unroll
            for (int i = 0; i < 2; ++i) {
                int row = wr*32 + i*16 + rl;
                af[i] = *(const short8*)((const char*)G + row*512 + ((((kt*16 + cA) ^ (row & 15)))<<4));
            }
            #pragma unroll
            for (int j = 0; j < 4; ++j) {
                int cn = wc*64 + j*16 + rl;
                bfr[j] = *(const short8*)&BsL[cn*128 + ((cA ^ (cn & 7))*8)];
            }
            #pragma unroll
            for (int i = 0; i < 2; ++i)
                #pragma unroll
                for (int j = 0; j < 4; ++j)
                    acc2[i][j] = __builtin_amdgcn_mfma_f32_16x16x32_bf16(af[i], bfr[j], acc2[i][j], 0, 0, 0);
        }
        __syncthreads();
    }
    #pragma unroll
    for (int j = 0; j < 4; ++j) {
        const int col_l = wc*64 + j*16 + rl;
        const float bs = b2[col_l];
        const int chunk = col_l >> 3, bo2 = (col_l & 7) << 1;
        #pragma unroll
        for (int i = 0; i < 2; ++i) {
            #pragma unroll
            for (int r = 0; r < 4; ++r) {
                const int row_l = wr*32 + i*16 + rq*4 + r;
                *(unsigned short*)((char*)AsL + row_l*256 + ((chunk ^ (row_l & 15))<<4) + bo2)
                    = f2b(acc2[i][j][r] + bs);
            }
        }
    }
    __syncthreads();
    float sj[8] = {}, qj[8] = {};
    #pragma unroll
    for (int it = 0; it < 4; ++it) {
        const int row_l = it*16 + (t >> 4), c = t & 15;
        ushort8v u = *(const ushort8v*)((const char*)AsL + row_l*256 + ((c ^ (row_l & 15))<<4));
        const size_t gbase = (size_t)(m0 + row_l)*128 + c*8;
        ushort8v rs = *(const ushort8v*)&Rsd[gbase];
        ushort8v o8;
        #pragma unroll
        for (int jj = 0; jj < 8; ++jj) {
            float v = b2f(u[jj]) + b2f(rs[jj])*snR[c*8+jj] + snR[128 + c*8 + jj];
            sj[jj] += v; qj[jj] += v*v;
            o8[jj] = f2b(v);
        }
        *(ushort8v*)&Cb[gbase] = o8;
    }
    #pragma unroll
    for (int jj = 0; jj < 8; ++jj) {
        sj[jj] += __shfl_xor(sj[jj], 16); qj[jj] += __shfl_xor(qj[jj], 16);
        sj[jj] += __shfl_xor(sj[jj], 32); qj[jj] += __shfl_xor(qj[jj], 32);
    }
    if ((lane >> 4) == 0) {
        #pragma unroll
        for (int jj = 0; jj < 8; ++jj) {
            sred[wid*128 + lane*8 + jj] = sj[jj];
            qred[wid*128 + lane*8 + jj] = qj[jj];
        }
    }
    __syncthreads();
    if (t < 128) {
        const int c2 = t >> 3, jj = t & 7;
        float s = sred[0*128 + c2*8 + jj] + sred[1*128 + c2*8 + jj]
                + sred[2*128 + c2*8 + jj] + sred[3*128 + c2*8 + jj];
        float q = qred[0*128 + c2*8 + jj] + qred[1*128 + c2*8 + jj]
                + qred[2*128 + c2*8 + jj] + qred[3*128 + c2*8 + jj];
        part[(size_t)blockIdx.x*256 + t]       = s;
        part[(size_t)blockIdx.x*256 + 128 + t] = q;
    }
}

// ---------------- BN stats finalize (1008 block-partials) ----------------
__global__ __launch_bounds__(256) void bnred(const float* __restrict__ part,
    const float* __restrict__ g, const float* __restrict__ b, float* __restrict__ sn)
{
    const int c = blockIdx.x, t = threadIdx.x;
    float s = 0.f, q = 0.f;
    for (int bid = t; bid < 1008; bid += 256) {
        s += part[(size_t)bid*256 + c];
        q += part[(size_t)bid*256 + 128 + c];
    }
    __shared__ float ls[256], lq[256];
    ls[t] = s; lq[t] = q;
    __syncthreads();
    for (int o = 128; o > 0; o >>= 1) {
        if (t < o) { ls[t] += ls[t+o]; lq[t] += lq[t+o]; }
        __syncthreads();
    }
    if (t == 0) {
        const float invM = 1.f / (float)RM;
        float mean = ls[0] * invM;
        float var  = fmaxf(lq[0]*invM - mean*mean, 0.f);
        float sc = g[c] * rsqrtf(var + 1e-5f);
        sn[c]       = sc;
        sn[128 + c] = b[c] - mean*sc;
    }
}

// ---------------- Weight fold ----------------
__global__ __launch_bounds__(256) void wfold(const unsigned short* __restrict__ WBs,
    const float* __restrict__ sn, const float* __restrict__ bsrc,
    unsigned short* __restrict__ WBd, float* __restrict__ bdst)
{
    const int t = threadIdx.x, wv = t >> 6, lane = t & 63;
    const int n = blockIdx.x*4 + wv;
    float w1 = b2f(WBs[(size_t)n*128 + lane]);
    float w2 = b2f(WBs[(size_t)n*128 + 64 + lane]);
    WBd[(size_t)n*128 + lane]      = f2b(sn[lane]*w1);
    WBd[(size_t)n*128 + 64 + lane] = f2b(sn[64+lane]*w2);
    float bacc = sn[128+lane]*w1 + sn[192+lane]*w2;
    #pragma unroll
    for (int msk = 1; msk < 64; msk <<= 1) bacc += __shfl_xor(bacc, msk);
    if (lane == 0) bdst[n] = bsrc[n] + bacc;
}

// ---------------- Attention: branchless no-max softmax (scores bounded |s|<~3) ----------------
template<int L>
__global__ __launch_bounds__(256) void attn_kernel(
    const unsigned short* __restrict__ qkv, const unsigned short* __restrict__ qkvP,
    const float* __restrict__ scale, unsigned short* __restrict__ ob)
{
    __shared__ float ks[4][504], vs[4][504], k0s[4][504];
    const int bn = blockIdx.x;
    const int t = threadIdx.x, wid = t >> 6, lane = t & 63;
    const int hd = blockIdx.y*4 + wid;
    const size_t rbase = (size_t)hd*RM + (size_t)bn*63;
    float qr[8] = {}, q0r[8] = {};
    if (lane < 63) {
        ushort8v ku = *(const ushort8v*)&qkv[((size_t)16*RM*8) + (rbase + lane)*8];
        ushort8v vu = *(const ushort8v*)&qkv[((size_t)32*RM*8) + (rbase + lane)*8];
        #pragma unroll
        for (int d = 0; d < 8; ++d) { ks[wid][lane*8+d] = b2f(ku[d]); vs[wid][lane*8+d] = b2f(vu[d]); }
        ushort8v qu = *(const ushort8v*)&qkv[(rbase + lane)*8];
        #pragma unroll
        for (int d = 0; d < 8; ++d) qr[d] = b2f(qu[d]);
        if constexpr (L > 0) {
            ushort8v k0u = *(const ushort8v*)&qkvP[((size_t)16*RM*8) + (rbase + lane)*8];
            #pragma unroll
            for (int d = 0; d < 8; ++d) k0s[wid][lane*8+d] = b2f(k0u[d]);
            ushort8v q0u = *(const ushort8v*)&qkvP[(rbase + lane)*8];
            #pragma unroll
            for (int d = 0; d < 8; ++d) q0r[d] = b2f(q0u[d]);
        }
    }
    __syncthreads();
    if (lane >= 63) return;
    const float scl  = scale[L];
    const float scl0 = (L > 0) ? scale[0] : 0.f;
    float sum = 0.f;
    float oa[8] = {};
    for (int j = 0; j < 63; ++j) {
        float s = 0.f;
        #pragma unroll
        for (int d = 0; d < 8; ++d) s += qr[d]*ks[wid][j*8+d];
        s *= scl;
        if constexpr (L > 0) {
            float s0 = 0.f;
            #pragma unroll
            for (int d = 0; d < 8; ++d) s0 += q0r[d]*k0s[wid][j*8+d];
            s += scl0 * s0;
        }
        float p = __expf(s);            // |s| <~ 3 by construction: no max-sub needed
        sum += p;
        #pragma unroll
        for (int d = 0; d < 8; ++d) oa[d] += p*vs[wid][j*8+d];
    }
    float inv = 1.f / sum;
    ushort8v u;
    #pragma unroll
    for (int d = 0; d < 8; ++d) u[d] = f2b(oa[d]*inv);
    *(ushort8v*)&ob[((size_t)hd*RM + (size_t)bn*63 + lane)*8] = u;
}

// ---------------- Head prep: blocks 0..62 fold weights (p-major), 63..158 fold bias ----------------
__global__ __launch_bounds__(256) void hprep(
    const float* __restrict__ hw, const float* __restrict__ hb,
    const float* __restrict__ sn,
    unsigned short* __restrict__ hwTf, float* __restrict__ hbf)
{
    const int t = threadIdx.x;
    if (blockIdx.x < 63) {
        const int p = blockIdx.x;
        for (int idx = t; idx < 16384; idx += 256) {
            int n = idx >> 7, d = idx & 127;
            unsigned short w = 0;
            if (n < 96) w = f2b(sn[d] * hw[(size_t)(d*63 + p)*96 + n]);
            hwTf[((size_t)p*128 + n)*128 + d] = w;
        }
    } else {
        const int n = blockIdx.x - 63;   // 0..95
        float acc = 0.f;
        for (int k = t; k < 8064; k += 256) {
            int d = (int)(((unsigned)k * 33289u) >> 21);
            acc += sn[128 + d] * hw[(size_t)k*96 + n];
        }
        __shared__ float ls[256];
        ls[t] = acc;
        __syncthreads();
        for (int o = 128; o > 0; o >>= 1) { if (t < o) ls[t] += ls[t+o]; __syncthreads(); }
        if (t == 0) hbf[n] = hb[n] + ls[0];
    }
}

// ---------------- Head MFMA GEMM: p-major 63-way K-split, coalesced A ----------------
__global__ __launch_bounds__(256) void mhead(
    const unsigned short* __restrict__ A, const unsigned short* __restrict__ BW,
    float* __restrict__ part)
{
    __shared__ __align__(16) unsigned short AsL[128*128];
    __shared__ __align__(16) unsigned short BsL[128*128];
    const int t = threadIdx.x;
    const int lane = t & 63, wid = t >> 6;
    const int wr = wid >> 1, wc = wid & 1;
    const int m0 = blockIdx.x * 128;
    const int p  = blockIdx.y;
    #pragma unroll
    for (int i = 0; i < 8; ++i) {
        int cid = i*256 + t;
        int row = cid >> 4, c = cid & 15;
        const unsigned short* ga = A + ((size_t)(m0+row)*63 + p)*128 + ((c ^ (row & 7))*8);
        __builtin_amdgcn_global_load_lds((const unsigned int*)ga,
            (unsigned int*)&AsL[(i*256 + wid*64)*8], 16, 0, 0);
    }
    #pragma unroll
    for (int i = 0; i < 8; ++i) {
        int cid = i*256 + t;
        int nr = cid >> 4, c = cid & 15;
        const unsigned short* gb = BW + ((size_t)p*128 + nr)*128 + ((c ^ (nr & 7))*8);
        __builtin_amdgcn_global_load_lds((const unsigned int*)gb,
            (unsigned int*)&BsL[(i*256 + wid*64)*8], 16, 0, 0);
    }
    __syncthreads();
    const int kh = lane >> 4, rl = lane & 15;
    f32x4 acc[4][3] = {};
    #pragma unroll
    for (int kq = 0; kq < 4; ++kq) {
        const int cA = kq*4 + kh;
        short8 af[4], bfr[3];
        #pragma unroll
        for (int i = 0; i < 4; ++i) {
            int row = wr*64 + i*16 + rl;
            af[i] = *(const short8*)&AsL[row*128 + ((cA ^ (row & 7))*8)];
        }
        #pragma unroll
        for (int j = 0; j < 3; ++j) {
            int cn = wc*48 + j*16 + rl;
            bfr[j] = *(const short8*)&BsL[cn*128 + ((cA ^ (cn & 7))*8)];
        }
        #pragma unroll
        for (int i = 0; i < 4; ++i)
            #pragma unroll
            for (int j = 0; j < 3; ++j)
                acc[i][j] = __builtin_amdgcn_mfma_f32_16x16x32_bf16(af[i], bfr[j], acc[i][j], 0, 0, 0);
    }
    const int rl2 = lane & 15, rq = lane >> 4;
    #pragma unroll
    for (int j = 0; j < 3; ++j) {
        const int col = wc*48 + j*16 + rl2;
        #pragma unroll
        for (int i = 0; i < 4; ++i) {
            const int rbase = m0 + wr*64 + i*16 + rq*4;
            #pragma unroll
            for (int r = 0; r < 4; ++r)
                part[((size_t)p*1024 + rbase + r)*96 + col] = acc[i][j][r];
        }
    }
}

__global__ __launch_bounds__(256) void head_reduce(const float* __restrict__ part,
    const float* __restrict__ hbf, float* __restrict__ out)
{
    int idx = blockIdx.x*256 + threadIdx.x;
    float s = hbf[idx % 96];
    #pragma unroll
    for (int blk = 0; blk < 63; ++blk) s += part[(size_t)blk*98304 + idx];
    out[idx] = s;
}

extern "C" void kernel_launch(void* const* d_in, const int* in_sizes, int n_in,
                              void* d_out, int out_size, void* d_ws, size_t ws_size,
                              hipStream_t stream) {
    const float* x    = (const float*)d_in[0];
    const float* adj  = (const float*)d_in[1];
    const float* sw   = (const float*)d_in[2];
    const float* sb   = (const float*)d_in[3];
    const float* mw   = (const float*)d_in[4];
    const float* mb   = (const float*)d_in[5];
    const float* Wp   = (const float*)d_in[6];
    const float* bp   = (const float*)d_in[7];
    const float* Wpos = (const float*)d_in[8];
    const float* Wq   = (const float*)d_in[9];
    const float* bq   = (const float*)d_in[10];
    const float* Wk   = (const float*)d_in[11];
    const float* bk   = (const float*)d_in[12];
    const float* Wv   = (const float*)d_in[13];
    const float* bv   = (const float*)d_in[14];
    const float* Wo   = (const float*)d_in[15];
    const float* bo   = (const float*)d_in[16];
    const float* scale= (const float*)d_in[17];
    const float* bn1g = (const float*)d_in[18];
    const float* bn1b = (const float*)d_in[19];
    const float* fw1  = (const float*)d_in[20];
    const float* fb1  = (const float*)d_in[21];
    const float* fw2  = (const float*)d_in[22];
    const float* fb2  = (const float*)d_in[23];
    const float* bn2g = (const float*)d_in[24];
    const float* bn2b = (const float*)d_in[25];
    const float* hw   = (const float*)d_in[26];
    const float* hb   = (const float*)d_in[27];
    float* out = (float*)d_out;

    // ---- workspace layout ----
    float* y     = (float*)d_ws;             // 524288
    float* part  = y     + 524288;           // 258048 (1008*256 BN partials)
    float* snorm = part  + 258048;           // 1024
    float* bcat  = snorm + 1024;             // 768
    float* bfold = bcat  + 768;              // 1024
    float* hbf   = bfold + 1024;             // 128
    float* hpart = hbf   + 128;              // 6193152 (63*1024*96)
    unsigned short* srcb = (unsigned short*)(hpart + 6193152);  // RM*128 bf16
    unsigned short* t1b  = srcb + 8257536;
    unsigned short* t2b  = t1b  + 8257536;
    unsigned short* g    = t2b  + 8257536;   // RM*256 bf16 (qkv scratch region)
    unsigned short* o_bf = g    + 16515072;  // [16][RM][8] bf16
    unsigned short* qkv0 = o_bf + 8257536;   // [48][RM][8] bf16
    unsigned short* qkv1 = qkv0 + 24772608;
    unsigned short* WB   = qkv1 + 24772608;  // 262144
    unsigned short* WF   = WB   + 262144;    // ff1_0 32768, ff1_1 32768, qkv1 49152
    unsigned short* hwTf = WF   + 131072;    // 63*128*128 = 1032192

    dgcn_kernel<<<4864, 256, 0, stream>>>(x, adj, sw, sb, mw, mb, y,
        Wq, Wk, Wv, Wo, fw1, fw2, bq, bk, bv, WB, bcat);
    patch_kernel<<<1024, 256, 0, stream>>>(y, Wp, bp, Wpos, srcb);

    // ---------------- layer 0 ----------------
    mgemm<0,1,0,false,false,3,128><<<1008, 256, 0, stream>>>(srcb, WB, bcat, nullptr, nullptr, qkv0, nullptr);
    attn_kernel<0><<<dim3(1024,4), 256, 0, stream>>>(qkv0, qkv0, scale, o_bf);
    mgemm<0,2,1,true,true,1,128><<<1008, 256, 0, stream>>>(o_bf, WB + 49152, bo, srcb, nullptr, t1b, part);
    bnred<<<128, 256, 0, stream>>>(part, bn1g, bn1b, snorm);                       // snorm0 = BN1 l0
    wfold<<<64, 256, 0, stream>>>(WB + 65536, snorm, fb1, WF, bfold);              // ff1 l0
    ffused<<<1008, 256, 0, stream>>>(t1b, WF, bfold, WB + 98304, fb2, t1b, snorm, t2b, part);
    bnred<<<128, 256, 0, stream>>>(part, bn2g, bn2b, snorm + 256);                 // snorm1 = BN2 l0
    wfold<<<96, 256, 0, stream>>>(WB + 131072, snorm + 256, bcat + 384, WF + 65536, bfold + 512); // qkv l1

    // ---------------- layer 1 ----------------
    mgemm<0,1,0,false,false,3,128><<<1008, 256, 0, stream>>>(t2b, WF + 65536, bfold + 512, nullptr, nullptr, qkv1, nullptr);
    attn_kernel<1><<<dim3(1024,4), 256, 0, stream>>>(qkv1, qkv0, scale, o_bf);
    mgemm<0,2,2,true,true,1,128><<<1008, 256, 0, stream>>>(o_bf, WB + 131072 + 49152, bo + 128, t2b, snorm + 256, t1b, part);
    bnred<<<128, 256, 0, stream>>>(part, bn1g + 128, bn1b + 128, snorm + 512);     // snorm2 = BN1 l1
    wfold<<<64, 256, 0, stream>>>(WB + 131072 + 65536, snorm + 512, fb1 + 256, WF + 32768, bfold + 256);
    ffused<<<1008, 256, 0, stream>>>(t1b, WF + 32768, bfold + 256, WB + 131072 + 98304, fb2 + 128, t1b, snorm + 512, t2b, part);
    bnred<<<128, 256, 0, stream>>>(part, bn2g + 128, bn2b + 128, snorm + 768);     // snorm3 = BN2 l1

    // ---------------- head (MFMA, BN folded; p-major K-split) ----------------
    hprep<<<159, 256, 0, stream>>>(hw, hb, snorm + 768, hwTf, hbf);
    mhead<<<dim3(8,63), 256, 0, stream>>>(t2b, hwTf, hpart);
    head_reduce<<<384, 256, 0, stream>>>(hpart, hbf, out);
}